// Round 9
// baseline (412.203 us; speedup 1.0000x reference)
//
#include <hip/hip_runtime.h>
#include <hip/hip_bf16.h>

typedef __attribute__((ext_vector_type(8))) short bf16x8;  // 8 bf16 (4 VGPRs)
typedef __attribute__((ext_vector_type(4))) short bf16x4;
typedef __attribute__((ext_vector_type(4))) float f32x4;   // MFMA C/D frag

__device__ __forceinline__ short f2bs(float v) {
  __hip_bfloat16 h = __float2bfloat16(v);
  return *reinterpret_cast<short*>(&h);
}

// ================ fused init: scat zero + stats zero + all weight transforms ================
// [0,8192) scat zero | [8192,10496) wtres rc1 | [10496,12800) wtres rc2 | [12800,12928) wtds1
// [12928,13440) wtds2 | [13440,14464) wtds3 | [14464,14720) wfc | [14720,14752) wsc
// [14752,14760) wproj | [14760] stats zero
__global__ __launch_bounds__(256) void k_wall(
    const float* __restrict__ rc1w, const float* __restrict__ rc2w,
    const float* __restrict__ d1w, const float* __restrict__ d2w,
    const float* __restrict__ d3w, const float* __restrict__ fcw,
    const float* __restrict__ c1w, const float* __restrict__ pw,
    short* __restrict__ wTr1, short* __restrict__ wTr2, short* __restrict__ wTds1,
    short* __restrict__ wTds2, short* __restrict__ wTds3, short* __restrict__ wfcbf,
    short* __restrict__ wsc, short* __restrict__ wproj,
    float* __restrict__ scat, float* __restrict__ stats) {
  __shared__ float ld[128 * 65];
  const int bx = blockIdx.x;
  const int tid = threadIdx.x;
  if (bx < 8192) {  // zero scat_pm (8388608 floats) via float4
    ((float4*)scat)[(size_t)bx * 256 + tid] = make_float4(0.f, 0.f, 0.f, 0.f);
  } else if (bx < 12800) {  // res-conv weights: [l][co][ci][3][3] -> [l][tap][co][ci]
    const float* src = (bx < 10496) ? rc1w : rc2w;
    short* dst = (bx < 10496) ? wTr1 : wTr2;
    const int i = ((bx - 8192) % 2304) * 256 + tid;
    if (i < 589824) {
      const int layer = i / 147456;
      const int rem = i % 147456;
      const int tap = rem / 16384;
      const int r2 = rem & 16383;
      const int co = r2 >> 7, ci = r2 & 127;
      dst[i] = f2bs(src[(((size_t)layer * 16384 + co * 128 + ci) * 9) + tap]);
    }
  } else if (bx < 14464) {  // ds weights: [co][ci][4][4] -> [tap][co][ci]
    int n, base;
    const float* src;
    short* dst;
    if (bx < 12928) { n = 32768; base = 12800; src = d1w; dst = wTds1; }
    else if (bx < 13440) { n = 131072; base = 12928; src = d2w; dst = wTds2; }
    else { n = 262144; base = 13440; src = d3w; dst = wTds3; }
    const int i = (bx - base) * 256 + tid;
    if (i < n) {
      const int COCI = n / 16;
      const int tap = i / COCI;
      const int rem = i % COCI;
      dst[i] = f2bs(src[(size_t)rem * 16 + tap]);
    }
  } else if (bx < 14720) {  // fc: [j][co*64+pix] -> [j][pix*128+co]
    const int j = bx - 14464;
    const float* sp = fcw + (size_t)j * 8192;
    for (int i = tid; i < 8192; i += 256) {
      const int co = i >> 6, pix = i & 63;
      ld[co * 65 + pix] = sp[i];
    }
    __syncthreads();
    short* dp = wfcbf + (size_t)j * 8192;
    for (int i = tid; i < 8192; i += 256) {
      const int pix = i >> 7, co = i & 127;
      dp[i] = f2bs(ld[co * 65 + pix]);
    }
  } else if (bx < 14752) {  // scatter weight: [co][ci] f32 -> bf16
    const int i = (bx - 14720) * 256 + tid;
    if (i < 8192) wsc[i] = f2bs(c1w[i]);
  } else if (bx < 14760) {  // project weight: [co][50] -> [co][64] zero-padded
    const int i = (bx - 14752) * 256 + tid;
    if (i < 2048) {
      const int co = i >> 6, k = i & 63;
      wproj[i] = (k < 50) ? f2bs(pw[co * 50 + k]) : (short)0;
    }
  } else {  // zero stats (2048 floats)
    for (int i = tid; i < 2048; i += 256) stats[i] = 0.f;
  }
}

// ================ scatter: entity GEMM (MFMA) + relu + coalesced scatter-add ================
__global__ __launch_bounds__(256) void k_scatmfma(const float* __restrict__ emb,
                                                  const int* __restrict__ xy,
                                                  const short* __restrict__ wsc,
                                                  float* __restrict__ scat_pm) {
  constexpr int CIP = 264;
  __shared__ short abf[64 * CIP];
  __shared__ int flat[64];
  const int tid = threadIdx.x;
  const int e0 = blockIdx.x * 64;
  const float4* eg = (const float4*)(emb + (size_t)e0 * 256);
  for (int i = tid; i < 4096; i += 256) {
    const int e = i >> 6, k4 = i & 63;
    const float4 v = eg[(size_t)e * 64 + k4];
    bf16x4 o;
    o[0] = f2bs(v.x); o[1] = f2bs(v.y); o[2] = f2bs(v.z); o[3] = f2bs(v.w);
    *(bf16x4*)(&abf[e * CIP + k4 * 4]) = o;
  }
  if (tid < 64) {
    const int* bp = xy + (size_t)(e0 + tid) * 16;
    int xv = 0, yv = 0;
#pragma unroll
    for (int j = 0; j < 8; ++j) xv = (xv << 1) | bp[j];
#pragma unroll
    for (int j = 8; j < 16; ++j) yv = (yv << 1) | bp[j];
    flat[tid] = (bp[0] != -1000000000)
                    ? (((e0 + tid) >> 9) * 4096 + ((yv >> 2) << 6) + (xv >> 2))
                    : -1;
  }
  __syncthreads();
  const int wq = __builtin_amdgcn_readfirstlane(tid >> 6);
  const int lane = tid & 63;
  const int l15 = lane & 15, quad = lane >> 4;
  f32x4 acc[2];
  acc[0] = (f32x4){0.f, 0.f, 0.f, 0.f};
  acc[1] = (f32x4){0.f, 0.f, 0.f, 0.f};
  const short* arow = &abf[(wq * 16 + l15) * CIP + quad * 8];
  const short* w0 = wsc + (size_t)l15 * 256 + quad * 8;
  const short* w1 = wsc + (size_t)(16 + l15) * 256 + quad * 8;
#pragma unroll
  for (int kk = 0; kk < 8; ++kk) {
    bf16x8 a = *(const bf16x8*)(arow + kk * 32);
    acc[0] = __builtin_amdgcn_mfma_f32_16x16x32_bf16(a, *(const bf16x8*)(w0 + kk * 32), acc[0], 0, 0, 0);
    acc[1] = __builtin_amdgcn_mfma_f32_16x16x32_bf16(a, *(const bf16x8*)(w1 + kk * 32), acc[1], 0, 0, 0);
  }
#pragma unroll
  for (int nt = 0; nt < 2; ++nt)
#pragma unroll
    for (int r = 0; r < 4; ++r) {
      const int e = wq * 16 + quad * 4 + r;
      const float v = acc[nt][r];
      const int f = flat[e];
      if (f >= 0 && v > 0.f)
        atomicAdd(&scat_pm[(size_t)f * 32 + nt * 16 + l15], v);
    }
}

// ================ project: concat + 1x1 conv + relu via MFMA -> pm bf16 ================
__global__ __launch_bounds__(256) void k_projmfma(const float* __restrict__ scat_pm,
                                                  const float* __restrict__ xin,
                                                  const short* __restrict__ wproj,
                                                  const float* __restrict__ pb,
                                                  short* __restrict__ h0pm) {
  constexpr int PK = 72;
  __shared__ short abf[128 * PK];
  const int tid = threadIdx.x;
  const int b = blockIdx.x >> 5;
  const int yx0 = (blockIdx.x & 31) << 7;
  const float4* sg = (const float4*)(scat_pm + ((size_t)(b * 4096 + yx0)) * 32);
  for (int i = tid; i < 1024; i += 256) {
    const int p = i >> 3, c4 = i & 7;
    const float4 v = sg[(size_t)p * 8 + c4];
    bf16x4 o;
    o[0] = f2bs(v.x); o[1] = f2bs(v.y); o[2] = f2bs(v.z); o[3] = f2bs(v.w);
    *(bf16x4*)(&abf[p * PK + c4 * 4]) = o;
  }
  for (int i = tid; i < 2304; i += 256) {
    const int run = i >> 7, p = i & 127;
    abf[p * PK + 32 + run] = f2bs(xin[(size_t)(b * 18 + run) * 4096 + yx0 + p]);
  }
  for (int i = tid; i < 2048; i += 256) {
    const int p = i >> 4, k = 50 + (i & 15);
    abf[p * PK + k] = 0;
  }
  __syncthreads();
  const int wq = __builtin_amdgcn_readfirstlane(tid >> 6);
  const int lane = tid & 63;
  const int l15 = lane & 15, quad = lane >> 4;
  f32x4 acc[2][2];
#pragma unroll
  for (int t = 0; t < 2; ++t)
#pragma unroll
    for (int n = 0; n < 2; ++n) acc[t][n] = (f32x4){0.f, 0.f, 0.f, 0.f};
  const short* wb0 = wproj + (size_t)l15 * 64 + quad * 8;
  const short* wb1 = wproj + (size_t)(16 + l15) * 64 + quad * 8;
#pragma unroll
  for (int kk = 0; kk < 2; ++kk) {
    const bf16x8 b0 = *(const bf16x8*)(wb0 + kk * 32);
    const bf16x8 b1 = *(const bf16x8*)(wb1 + kk * 32);
#pragma unroll
    for (int t = 0; t < 2; ++t) {
      const int pix = (wq * 2 + t) * 16 + l15;
      bf16x8 a = *(const bf16x8*)(&abf[pix * PK + quad * 8 + kk * 32]);
      acc[t][0] = __builtin_amdgcn_mfma_f32_16x16x32_bf16(a, b0, acc[t][0], 0, 0, 0);
      acc[t][1] = __builtin_amdgcn_mfma_f32_16x16x32_bf16(a, b1, acc[t][1], 0, 0, 0);
    }
  }
#pragma unroll
  for (int t = 0; t < 2; ++t)
#pragma unroll
    for (int n = 0; n < 2; ++n) {
      const int co = n * 16 + l15;
      const float bv = pb[co];
#pragma unroll
      for (int r = 0; r < 4; ++r) {
        const int pix = (wq * 2 + t) * 16 + quad * 4 + r;
        float v = acc[t][n][r] + bv;
        v = v > 0.f ? v : 0.f;
        h0pm[((size_t)(b * 4096 + yx0 + pix)) * 32 + co] = f2bs(v);
      }
    }
}

// ---------------- 4x4 s2 p1 conv + bias + relu via MFMA, pm bf16 in/out ----------------
template <int CIN, int COUT, int HIN, int ROWSO, int COSPLIT, int MT, int NT, int OUTMODE>
__global__ __launch_bounds__(256) void k_ds2(const short* __restrict__ inpm,
                                             const short* __restrict__ wT,
                                             const float* __restrict__ bias,
                                             short* __restrict__ outbf,
                                             float* __restrict__ outf,
                                             float* __restrict__ msf) {
  constexpr int HOUT = HIN / 2;
  constexpr int ROWS = 2 * ROWSO + 2;
  constexpr int COLS = HIN + 2;
  constexpr int CHUNKS = CIN / 8;
  constexpr int KK = CIN / 32;
  constexpr int CIPAD = CIN + 8;
  constexpr int NHO = HOUT / ROWSO;
  __shared__ short lin[ROWS * COLS * CIPAD];
  const int tid = threadIdx.x;
  int bx = blockIdx.x;
  const int co_blk = (COSPLIT > 1) ? (bx % COSPLIT) : 0;
  if (COSPLIT > 1) bx /= COSPLIT;
  const int hoblk = bx % NHO;
  const int b = bx / NHO;
  for (int i = tid; i < ROWS * COLS * CHUNKS; i += 256) {
    const int ch = i % CHUNKS;
    const int pixv = i / CHUNKS;
    const int r = pixv / COLS, c = pixv % COLS;
    const int hi = 2 * ROWSO * hoblk - 1 + r;
    const int wc = c - 1;
    bf16x8 v = (bf16x8)(short)0;
    if (hi >= 0 && hi < HIN && wc >= 0 && wc < HIN)
      v = *(const bf16x8*)(inpm + ((size_t)(b * HIN + hi) * HIN + wc) * CIN + ch * 8);
    *(bf16x8*)(&lin[(r * COLS + c) * CIPAD + ch * 8]) = v;
  }
  __syncthreads();
  const int wq = __builtin_amdgcn_readfirstlane(tid >> 6);
  const int lane = tid & 63;
  const int l15 = lane & 15, quad = lane >> 4;
  const int mtile = (MT > 1) ? (wq % MT) : 0;
  const int cogrp = wq / MT;
  const int cobase = co_blk * (COUT / COSPLIT) + cogrp * (NT * 16);
  const int p = mtile * 16 + l15;
  const int dr = p / HOUT;
  const int col = p % HOUT;
  f32x4 acc[NT];
#pragma unroll
  for (int n = 0; n < NT; ++n) acc[n] = (f32x4){0.f, 0.f, 0.f, 0.f};
  const short* wrow = wT + (size_t)(cobase + l15) * CIN + quad * 8;
  for (int ky = 0; ky < 4; ++ky) {
    for (int kx = 0; kx < 4; ++kx) {
      const short* arow = &lin[((2 * dr + ky) * COLS + 2 * col + kx) * CIPAD + quad * 8];
      const short* wt = wrow + (size_t)(ky * 4 + kx) * COUT * CIN;
#pragma unroll
      for (int kk = 0; kk < KK; ++kk) {
        bf16x8 a = *(const bf16x8*)(arow + kk * 32);
#pragma unroll
        for (int n = 0; n < NT; ++n) {
          bf16x8 bf = *(const bf16x8*)(wt + n * 16 * CIN + kk * 32);
          acc[n] = __builtin_amdgcn_mfma_f32_16x16x32_bf16(a, bf, acc[n], 0, 0, 0);
        }
      }
    }
  }
#pragma unroll
  for (int n = 0; n < NT; ++n) {
    const int co = cobase + n * 16 + l15;
    const float bv = bias[co];
#pragma unroll
    for (int r = 0; r < 4; ++r) {
      const int pp = mtile * 16 + quad * 4 + r;
      const int dr2 = pp / HOUT;
      const int c2 = pp % HOUT;
      const int ho = hoblk * ROWSO + dr2;
      float v = acc[n][r] + bv;
      v = v > 0.f ? v : 0.f;
      const size_t o = ((size_t)b * HOUT * HOUT + ho * HOUT + c2) * COUT + co;
      outbf[o] = f2bs(v);
      if (OUTMODE == 1) {
        outf[o] = v;
        msf[o] = v;
      }
    }
  }
}

// ---------------- 3x3 s1 p1 conv on 8x8 via MFMA, fused stats ----------------
// BNIN=0: stage pm bf16. BNIN=1: stage BN(statsIn)+relu of pm f32 (conv2).
// BNIN=2: stage relu(BN2(fin)+ident) (fused residual epilogue of previous block);
//         cobase==0 blocks also write houtpm (next identity) and mspm += v.
template <int BNIN>
__global__ __launch_bounds__(256) void k_resmfma(const short* __restrict__ hbfin,
                                                 const float* __restrict__ fin,
                                                 const float* __restrict__ statsIn,
                                                 const float* __restrict__ gIn,
                                                 const float* __restrict__ bIn,
                                                 const float* __restrict__ identpm,
                                                 float* __restrict__ houtpm,
                                                 float* __restrict__ mspm,
                                                 const short* __restrict__ wT,
                                                 float* __restrict__ outpm,
                                                 float* __restrict__ statsOut) {
  constexpr int CIPAD = 136;
  __shared__ short lin[100 * CIPAD];
  __shared__ float bnsc[128], bnsh[128];
  const int tid = threadIdx.x;
  const int b = blockIdx.x >> 3;
  const int cobase = (blockIdx.x & 7) << 4;
  if (BNIN >= 1) {
    if (tid < 128) {
      const float mu = statsIn[tid] * (1.f / 4096.f);
      const float var = statsIn[128 + tid] * (1.f / 4096.f) - mu * mu;
      const float sc = gIn[tid] * rsqrtf(var + 1e-5f);
      bnsc[tid] = sc;
      bnsh[tid] = bIn[tid] - mu * sc;
    }
    __syncthreads();
  }
  if (BNIN == 0) {
    const short* hb = hbfin + ((size_t)b << 13);
    for (int i = tid; i < 1600; i += 256) {
      const int pixel = i >> 4, ch = i & 15;
      const int r = pixel / 10, c = pixel % 10;
      bf16x8 v = (bf16x8)(short)0;
      if (r >= 1 && r <= 8 && c >= 1 && c <= 8)
        v = *(const bf16x8*)(hb + (((r - 1) << 3) + (c - 1)) * 128 + ch * 8);
      *(bf16x8*)(&lin[pixel * CIPAD + ch * 8]) = v;
    }
  } else if (BNIN == 1) {
    const float* fb = fin + ((size_t)b << 13);
    for (int i = tid; i < 3200; i += 256) {
      const int pixel = i >> 5, c4 = i & 31;
      const int r = pixel / 10, c = pixel % 10;
      bf16x4 o = (bf16x4)(short)0;
      if (r >= 1 && r <= 8 && c >= 1 && c <= 8) {
        const float4 x = *(const float4*)(fb + (size_t)(((r - 1) << 3) + (c - 1)) * 128 + c4 * 4);
        const float xv[4] = {x.x, x.y, x.z, x.w};
#pragma unroll
        for (int k = 0; k < 4; ++k) {
          const int ci = c4 * 4 + k;
          const float v = xv[k] * bnsc[ci] + bnsh[ci];
          o[k] = f2bs(v > 0.f ? v : 0.f);
        }
      }
      *(bf16x4*)(&lin[pixel * CIPAD + c4 * 4]) = o;
    }
  } else {
    const float* fb = fin + ((size_t)b << 13);
    const float* ib = identpm + ((size_t)b << 13);
    float* hb = houtpm + ((size_t)b << 13);
    float* mb = mspm + ((size_t)b << 13);
    const bool wr = (cobase == 0);
    for (int i = tid; i < 3200; i += 256) {
      const int pixel = i >> 5, c4 = i & 31;
      const int r = pixel / 10, c = pixel % 10;
      bf16x4 o = (bf16x4)(short)0;
      if (r >= 1 && r <= 8 && c >= 1 && c <= 8) {
        const size_t gi = (size_t)(((r - 1) << 3) + (c - 1)) * 128 + c4 * 4;
        const float4 x = *(const float4*)(fb + gi);
        const float4 idv = *(const float4*)(ib + gi);
        const float xv[4] = {x.x, x.y, x.z, x.w};
        const float iv[4] = {idv.x, idv.y, idv.z, idv.w};
        float vv[4];
#pragma unroll
        for (int k = 0; k < 4; ++k) {
          const int ci = c4 * 4 + k;
          float v = xv[k] * bnsc[ci] + bnsh[ci] + iv[k];
          v = v > 0.f ? v : 0.f;
          vv[k] = v;
          o[k] = f2bs(v);
        }
        if (wr) {
          *(float4*)(hb + gi) = make_float4(vv[0], vv[1], vv[2], vv[3]);
          const float4 m = *(const float4*)(mb + gi);
          *(float4*)(mb + gi) = make_float4(m.x + vv[0], m.y + vv[1], m.z + vv[2], m.w + vv[3]);
        }
      }
      *(bf16x4*)(&lin[pixel * CIPAD + c4 * 4]) = o;
    }
  }
  __syncthreads();
  const int wq = __builtin_amdgcn_readfirstlane(tid >> 6);
  const int lane = tid & 63;
  const int l15 = lane & 15, quad = lane >> 4;
  const int p = wq * 16 + l15;
  const int py = p >> 3, px = p & 7;
  f32x4 acc = (f32x4){0.f, 0.f, 0.f, 0.f};
  const short* wrow = wT + (size_t)(cobase + l15) * 128 + quad * 8;
  for (int t = 0; t < 9; ++t) {
    const int ky = t / 3, kx = t % 3;
    const short* arow = &lin[((py + ky) * 10 + px + kx) * CIPAD + quad * 8];
    const short* wt = wrow + (size_t)t * 16384;
#pragma unroll
    for (int kk = 0; kk < 4; ++kk) {
      bf16x8 a = *(const bf16x8*)(arow + kk * 32);
      bf16x8 bf = *(const bf16x8*)(wt + kk * 32);
      acc = __builtin_amdgcn_mfma_f32_16x16x32_bf16(a, bf, acc, 0, 0, 0);
    }
  }
  float* ob = outpm + ((size_t)b << 13);
  const int co = cobase + l15;
  float s = 0.f, q = 0.f;
#pragma unroll
  for (int r = 0; r < 4; ++r) {
    const float v = acc[r];
    ob[(size_t)(wq * 16 + quad * 4 + r) * 128 + co] = v;
    s += v;
    q += v * v;
  }
  s += __shfl_down(s, 32); q += __shfl_down(q, 32);
  s += __shfl_down(s, 16); q += __shfl_down(q, 16);
  if (lane < 16) {
    atomicAdd(&statsOut[co], s);
    atomicAdd(&statsOut[128 + co], q);
  }
}

// ---------------- final: BN2 + identity + relu + ms-add + transpose-out + bf16 h ----------------
__global__ __launch_bounds__(256) void k_bnfinal(const float* __restrict__ tmp2pm,
                                                 const float* __restrict__ stats,
                                                 const float* __restrict__ g,
                                                 const float* __restrict__ bb,
                                                 const float* __restrict__ identpm,
                                                 const float* __restrict__ mspm,
                                                 float* __restrict__ out0,
                                                 short* __restrict__ hbf) {
  __shared__ float t[64 * 132];
  __shared__ float bnsc[128], bnsh[128];
  const int b = blockIdx.x;
  const int tid = threadIdx.x;
  if (tid < 128) {
    const float mu = stats[tid] * (1.f / 4096.f);
    const float var = stats[128 + tid] * (1.f / 4096.f) - mu * mu;
    const float sc = g[tid] * rsqrtf(var + 1e-5f);
    bnsc[tid] = sc;
    bnsh[tid] = bb[tid] - mu * sc;
  }
  __syncthreads();
  const size_t base = (size_t)b << 13;
  for (int i = tid; i < 8192; i += 256) {
    const int co = i & 127, pix = i >> 7;
    float v = tmp2pm[base + i] * bnsc[co] + bnsh[co] + identpm[base + i];
    v = v > 0.f ? v : 0.f;
    hbf[base + i] = f2bs(v);
    t[pix * 132 + co] = mspm[base + i] + v;
  }
  __syncthreads();
  float* dp = out0 + base;
  for (int i = tid; i < 8192; i += 256) {
    const int co = i >> 6, pix = i & 63;
    dp[i] = t[pix * 132 + co];
  }
}

// ---------------- FC via MFMA: k-split partials ----------------
__global__ __launch_bounds__(256) void k_fcmfma(const short* __restrict__ hbf,
                                                const short* __restrict__ wbf,
                                                float* __restrict__ part) {
  const int nb = blockIdx.x & 3;
  const int kb = blockIdx.x >> 2;
  const int wq = __builtin_amdgcn_readfirstlane((int)(threadIdx.x >> 6));
  const int lane = threadIdx.x & 63;
  const int l15 = lane & 15, quad = lane >> 4;
  const int k0 = kb * 256 + quad * 8;
  const short* wp = wbf + (size_t)(nb * 64 + wq * 16 + l15) * 8192 + k0;
  const short* hp = hbf + (size_t)l15 * 8192 + k0;
  f32x4 acc[4];
#pragma unroll
  for (int m = 0; m < 4; ++m) acc[m] = (f32x4){0.f, 0.f, 0.f, 0.f};
  for (int ks = 0; ks < 8; ++ks) {
    bf16x8 bfr = *(const bf16x8*)(wp + ks * 32);
#pragma unroll
    for (int m = 0; m < 4; ++m) {
      bf16x8 a = *(const bf16x8*)(hp + (size_t)m * 16 * 8192 + ks * 32);
      acc[m] = __builtin_amdgcn_mfma_f32_16x16x32_bf16(a, bfr, acc[m], 0, 0, 0);
    }
  }
#pragma unroll
  for (int m = 0; m < 4; ++m)
#pragma unroll
    for (int r = 0; r < 4; ++r) {
      const int b = m * 16 + quad * 4 + r;
      part[((size_t)kb * 64 + b) * 256 + nb * 64 + wq * 16 + l15] = acc[m][r];
    }
}

__global__ __launch_bounds__(256) void k_fcred(const float* __restrict__ part,
                                               const float* __restrict__ bias,
                                               float* __restrict__ out1) {
  const int idx = blockIdx.x * 256 + threadIdx.x;
  const int j = idx & 255;
  float s = 0.f;
#pragma unroll 8
  for (int kb = 0; kb < 32; ++kb) s += part[(size_t)kb * 16384 + idx];
  const float v = s + bias[j];
  out1[idx] = v > 0.f ? v : 0.f;
}

extern "C" void kernel_launch(void* const* d_in, const int* in_sizes, int n_in,
                              void* d_out, int out_size, void* d_ws, size_t ws_size,
                              hipStream_t stream) {
  const float* xin = (const float*)d_in[0];
  const float* emb = (const float*)d_in[1];
  const int* xy = (const int*)d_in[2];
  const float* c1w = (const float*)d_in[3];
  const float* pw = (const float*)d_in[4];
  const float* pb = (const float*)d_in[5];
  const float* d1w = (const float*)d_in[6];
  const float* d1b = (const float*)d_in[7];
  const float* d2w = (const float*)d_in[8];
  const float* d2b = (const float*)d_in[9];
  const float* d3w = (const float*)d_in[10];
  const float* d3b = (const float*)d_in[11];
  const float* rc1w = (const float*)d_in[12];
  const float* rbn1g = (const float*)d_in[13];
  const float* rbn1b = (const float*)d_in[14];
  const float* rc2w = (const float*)d_in[15];
  const float* rbn2g = (const float*)d_in[16];
  const float* rbn2b = (const float*)d_in[17];
  const float* fcw = (const float*)d_in[18];
  const float* fcb = (const float*)d_in[19];

  float* out0 = (float*)d_out;   // map_skip [64,128,8,8] f32
  float* out1 = out0 + 524288;   // embedded_spatial [64,256] f32

  float* F = (float*)d_ws;
  float* scat = F + 0;           // scat_pm [64][4096][32] f32 — dead after projmfma; reused:
  float* h1pm_f = F + 0;
  float* h2pm_f = F + 2097152;
  float* hApm = F + 3145728;
  float* hBpm = F + 3670016;
  float* tmppm = F + 4194304;
  float* tmp2pm = F + 4718592;
  float* mspm = F + 5242880;
  short* pmbfA = (short*)(F + 5767168);
  short* hfinbf = (short*)(F + 6029312);
  float* stats = F + 6291456;
  float* fcpart = F + 6293504;   // ends 6817792 < 8388608
  short* h0pm = (short*)(F + 8388608);    // [64][4096][32] bf16
  short* wfcbf = (short*)(F + 12582912);
  short* wTr1 = (short*)(F + 13631488);
  short* wTr2 = wTr1 + 589824;
  short* wTds1 = wTr2 + 589824;
  short* wTds2 = wTds1 + 32768;
  short* wTds3 = wTds2 + 131072;
  short* wsc = wTds3 + 262144;
  short* wproj = wsc + 8192;

  // init: scat zero + stats zero + all weight transforms, one launch
  k_wall<<<14761, 256, 0, stream>>>(rc1w, rc2w, d1w, d2w, d3w, fcw, c1w, pw,
                                    wTr1, wTr2, wTds1, wTds2, wTds3, wfcbf, wsc, wproj,
                                    scat, stats);
  k_scatmfma<<<512, 256, 0, stream>>>(emb, xy, wsc, scat);
  k_projmfma<<<2048, 256, 0, stream>>>(scat, xin, wproj, pb, h0pm);
  short* h1pm = (short*)h1pm_f;
  short* h2pm = (short*)h2pm_f;
  k_ds2<32, 64, 64, 2, 1, 4, 4, 0><<<1024, 256, 0, stream>>>(h0pm, wTds1, d1b, h1pm, hApm, mspm);
  k_ds2<64, 128, 32, 1, 1, 1, 2, 0><<<1024, 256, 0, stream>>>(h1pm, wTds2, d2b, h2pm, hApm, mspm);
  // ds3: triple store — h_0 bf16 (conv1_0 staging), h_0 f32 (identity), ms seed
  k_ds2<128, 128, 16, 2, 2, 1, 1, 1><<<512, 256, 0, stream>>>(h2pm, wTds3, d3b, pmbfA, hApm, mspm);

  // res chain: identity ping-pong hApm/hBpm; bnadd fused into next conv1 (BNIN=2)
  float* ident = hApm;   // h_0
  float* identN = hBpm;
  for (int i = 0; i < 4; ++i) {
    float* sA = stats + i * 512;
    float* sB = stats + i * 512 + 256;
    if (i == 0) {
      k_resmfma<0><<<512, 256, 0, stream>>>(pmbfA, nullptr, nullptr, nullptr, nullptr,
                                            nullptr, nullptr, nullptr,
                                            wTr1, tmppm, sA);
    } else {
      float* sBp = stats + (i - 1) * 512 + 256;
      k_resmfma<2><<<512, 256, 0, stream>>>(nullptr, tmp2pm, sBp, rbn2g + (i - 1) * 128,
                                            rbn2b + (i - 1) * 128, ident, identN, mspm,
                                            wTr1 + (size_t)i * 147456, tmppm, sA);
      float* sw = ident; ident = identN; identN = sw;  // identity is now h_i
    }
    k_resmfma<1><<<512, 256, 0, stream>>>(nullptr, tmppm, sA, rbn1g + i * 128, rbn1b + i * 128,
                                          nullptr, nullptr, nullptr,
                                          wTr2 + (size_t)i * 147456, tmp2pm, sB);
  }
  // final: BN2_3 + identity(h_3) + relu + ms add + transpose to out0 + bf16 h for fc
  k_bnfinal<<<64, 256, 0, stream>>>(tmp2pm, stats + 3 * 512 + 256, rbn2g + 384, rbn2b + 384,
                                    ident, mspm, out0, hfinbf);
  k_fcmfma<<<128, 256, 0, stream>>>(hfinbf, wfcbf, fcpart);
  k_fcred<<<64, 256, 0, stream>>>(fcpart, fcb, out1);
}